// Round 1
// baseline (4903.481 us; speedup 1.0000x reference)
//
#include <hip/hip_runtime.h>
#include <math.h>

#define BM 64
#define BN 64
#define BK 32

// ---------------------------------------------------------------------------
// Generic 64x64 tile GEMM: C_tile[m,n] += sum_k A[m0+m, k] * B[n0+n, k]
// A: [arows, Kd] row-major (lda), B: [brows, Kd] row-major (ldb).
// 256 threads, each computes 4x4 outputs. Zero-pads edges.
// ---------------------------------------------------------------------------
__device__ __forceinline__ void gemm_tile(
    const float* __restrict__ A, int lda, int arows,
    const float* __restrict__ B, int ldb, int brows,
    int Kd, int m0, int n0,
    float (&acc)[4][4],
    float (*As)[BM + 4], float (*Bs)[BN + 4])
{
    const int tid = threadIdx.x;
    const int lr = tid >> 3;   // 0..31
    const int lk = tid & 7;    // 0..7  (k-float4 index)
    const int tm = tid >> 4;   // 0..15
    const int tn = tid & 15;   // 0..15

    for (int kb = 0; kb < Kd; kb += BK) {
        __syncthreads();
        const int gk = kb + lk * 4;
        const bool kok = (gk + 4) <= Kd;   // all K dims are multiples of 4
#pragma unroll
        for (int rr = 0; rr < 2; ++rr) {
            const int r = lr + rr * 32;
            // A tile
            float4 v = make_float4(0.f, 0.f, 0.f, 0.f);
            const int gm = m0 + r;
            if (kok && gm < arows)
                v = *(const float4*)(A + (size_t)gm * lda + gk);
            As[lk * 4 + 0][r] = v.x;
            As[lk * 4 + 1][r] = v.y;
            As[lk * 4 + 2][r] = v.z;
            As[lk * 4 + 3][r] = v.w;
            // B tile
            float4 w = make_float4(0.f, 0.f, 0.f, 0.f);
            const int gn = n0 + r;
            if (kok && gn < brows)
                w = *(const float4*)(B + (size_t)gn * ldb + gk);
            Bs[lk * 4 + 0][r] = w.x;
            Bs[lk * 4 + 1][r] = w.y;
            Bs[lk * 4 + 2][r] = w.z;
            Bs[lk * 4 + 3][r] = w.w;
        }
        __syncthreads();
#pragma unroll
        for (int k = 0; k < BK; ++k) {
            const float4 a = *(const float4*)&As[k][tm * 4];
            const float4 b = *(const float4*)&Bs[k][tn * 4];
            acc[0][0] += a.x * b.x; acc[0][1] += a.x * b.y; acc[0][2] += a.x * b.z; acc[0][3] += a.x * b.w;
            acc[1][0] += a.y * b.x; acc[1][1] += a.y * b.y; acc[1][2] += a.y * b.z; acc[1][3] += a.y * b.w;
            acc[2][0] += a.z * b.x; acc[2][1] += a.z * b.y; acc[2][2] += a.z * b.z; acc[2][3] += a.z * b.w;
            acc[3][0] += a.w * b.x; acc[3][1] += a.w * b.y; acc[3][2] += a.w * b.z; acc[3][3] += a.w * b.w;
        }
    }
}

__device__ __forceinline__ void store_tile(
    float* __restrict__ C, int ldc, int M, int N,
    int m0, int n0, const float (&acc)[4][4], float scale)
{
    const int tm = threadIdx.x >> 4, tn = threadIdx.x & 15;
    const int n = n0 + tn * 4;
#pragma unroll
    for (int i = 0; i < 4; ++i) {
        const int m = m0 + tm * 4 + i;
        if (m < M && n < N) {  // N is always a multiple of 4 -> full float4 ok
            float4 v = make_float4(acc[i][0] * scale, acc[i][1] * scale,
                                   acc[i][2] * scale, acc[i][3] * scale);
            *(float4*)(C + (size_t)m * ldc + n) = v;
        }
    }
}

// ---------------------------------------------------------------------------
// Stage kernels
// ---------------------------------------------------------------------------

// Kt[z][o,n] = sum_k Wk[h,o,k] * emb_all[b,n,k]     (z = local_b*4 + h)
__global__ __launch_bounds__(256) void k_kt(const float* __restrict__ emb_all,
                                            const float* __restrict__ Wk,
                                            float* __restrict__ Kt, int b0)
{
    __shared__ float As[BK][BM + 4], Bs[BK][BN + 4];
    const int z = blockIdx.z, h = z & 3, b = b0 + (z >> 2);
    const float* A = Wk + (size_t)h * 960 * 960;
    const float* B = emb_all + (size_t)b * 196 * 960;
    const int m0 = blockIdx.y * BM, n0 = blockIdx.x * BN;
    float acc[4][4] = {};
    gemm_tile(A, 960, 960, B, 960, 196, 960, m0, n0, acc, As, Bs);
    store_tile(Kt + (size_t)z * 960 * 196, 196, 960, 196, m0, n0, acc, 1.f);
}

// V[z][n,o] = sum_k emb_all[b,n,k] * Wv[h,o,k]
__global__ __launch_bounds__(256) void k_v(const float* __restrict__ emb_all,
                                           const float* __restrict__ Wv,
                                           float* __restrict__ V, int b0)
{
    __shared__ float As[BK][BM + 4], Bs[BK][BN + 4];
    const int z = blockIdx.z, h = z & 3, b = b0 + (z >> 2);
    const float* A = emb_all + (size_t)b * 196 * 960;
    const float* B = Wv + (size_t)h * 960 * 960;
    const int m0 = blockIdx.y * BM, n0 = blockIdx.x * BN;
    float acc[4][4] = {};
    gemm_tile(A, 960, 196, B, 960, 960, 960, m0, n0, acc, As, Bs);
    store_tile(V + (size_t)z * 196 * 960, 960, 196, 960, m0, n0, acc, 1.f);
}

// Qt[z][ccat,n] = sum_d Wq_br[h, c_local, d] * emb_br[b, n, d]
__global__ __launch_bounds__(256) void k_q(
    const float* __restrict__ e1, const float* __restrict__ e2,
    const float* __restrict__ e3, const float* __restrict__ e4,
    const float* __restrict__ Wq1, const float* __restrict__ Wq2,
    const float* __restrict__ Wq3, const float* __restrict__ Wq4,
    float* __restrict__ Qt, int b0)
{
    __shared__ float As[BK][BM + 4], Bs[BK][BN + 4];
    const int z = blockIdx.z, h = z & 3, b = b0 + (z >> 2);
    const int rt = blockIdx.y;
    const float *Wq, *emb;
    int roff, Ci;
    if (rt < 1)      { roff = rt * 64;       Ci = 64;  Wq = Wq1; emb = e1; }
    else if (rt < 3) { roff = (rt - 1) * 64; Ci = 128; Wq = Wq2; emb = e2; }
    else if (rt < 7) { roff = (rt - 3) * 64; Ci = 256; Wq = Wq3; emb = e3; }
    else             { roff = (rt - 7) * 64; Ci = 512; Wq = Wq4; emb = e4; }
    const float* A = Wq + (size_t)h * Ci * Ci + (size_t)roff * Ci;
    const float* B = emb + (size_t)b * 196 * Ci;
    const int n0 = blockIdx.x * BN;
    float acc[4][4] = {};
    gemm_tile(A, Ci, 64, B, Ci, 196, Ci, 0, n0, acc, As, Bs);
    store_tile(Qt + (size_t)z * 960 * 196, 196, 960, 196, rt * 64, n0, acc, 1.f);
}

// S[z][c,o] = (1/sqrt(960)) * sum_n Qt[z][c,n] * Kt[z][o,n]  (+ stats)
__global__ __launch_bounds__(256) void k_s(const float* __restrict__ Qt,
                                           const float* __restrict__ Kt,
                                           float* __restrict__ S,
                                           float* __restrict__ stats)
{
    __shared__ float As[BK][BM + 4], Bs[BK][BN + 4];
    __shared__ float2 red[256];
    const int z = blockIdx.z;
    const float* A = Qt + (size_t)z * 960 * 196;
    const float* B = Kt + (size_t)z * 960 * 196;
    const int m0 = blockIdx.y * BM, n0 = blockIdx.x * BN;
    float acc[4][4] = {};
    gemm_tile(A, 196, 960, B, 196, 960, 196, m0, n0, acc, As, Bs);
    const float scale = 0.03227486121839514f;  // 1/sqrt(960)
    store_tile(S + (size_t)z * 960 * 960, 960, 960, 960, m0, n0, acc, scale);
    // block-local stats (whole tile belongs to one branch: BM=64 divides offsets)
    float s = 0.f, q = 0.f;
#pragma unroll
    for (int i = 0; i < 4; ++i)
#pragma unroll
        for (int j = 0; j < 4; ++j) {
            const float v = acc[i][j] * scale;
            s += v; q += v * v;
        }
    const int tid = threadIdx.x;
    red[tid] = make_float2(s, q);
    __syncthreads();
    for (int off = 128; off > 0; off >>= 1) {
        if (tid < off) {
            red[tid].x += red[tid + off].x;
            red[tid].y += red[tid + off].y;
        }
        __syncthreads();
    }
    if (tid == 0) {
        const int rt = blockIdx.y;
        const int br = (rt < 1) ? 0 : (rt < 3) ? 1 : (rt < 7) ? 2 : 3;
        float* st = stats + ((size_t)z * 4 + br) * 2;
        atomicAdd(st + 0, red[0].x);
        atomicAdd(st + 1, red[0].y);
    }
}

// Row softmax with InstanceNorm temperature (mean shift cancels in softmax).
__global__ __launch_bounds__(256) void k_sm(float* __restrict__ S,
                                            const float* __restrict__ stats)
{
    const int row = blockIdx.x;            // z*960 + c
    const int z = row / 960, c = row % 960;
    const int br = (c < 64) ? 0 : (c < 192) ? 1 : (c < 448) ? 2 : 3;
    const int Ci = (br == 0) ? 64 : (br == 1) ? 128 : (br == 2) ? 256 : 512;
    const float* st = stats + ((size_t)z * 4 + br) * 2;
    const float cnt = (float)Ci * 960.f;
    const float mean = st[0] / cnt;
    const float var = st[1] / cnt - mean * mean;
    const float rs = rsqrtf(var + 1e-5f);
    float* p = S + (size_t)z * 960 * 960 + (size_t)c * 960;
    const int tid = threadIdx.x;
    __shared__ float red[256];

    float4 x = make_float4(0.f, 0.f, 0.f, 0.f);
    float m = -1e30f;
    if (tid < 240) {
        x = *(const float4*)(p + tid * 4);
        x.x *= rs; x.y *= rs; x.z *= rs; x.w *= rs;
        m = fmaxf(fmaxf(x.x, x.y), fmaxf(x.z, x.w));
    }
    red[tid] = m;
    __syncthreads();
    for (int off = 128; off > 0; off >>= 1) {
        if (tid < off) red[tid] = fmaxf(red[tid], red[tid + off]);
        __syncthreads();
    }
    const float mx = red[0];
    __syncthreads();

    float4 e = make_float4(0.f, 0.f, 0.f, 0.f);
    float sum = 0.f;
    if (tid < 240) {
        e.x = __expf(x.x - mx); e.y = __expf(x.y - mx);
        e.z = __expf(x.z - mx); e.w = __expf(x.w - mx);
        sum = e.x + e.y + e.z + e.w;
    }
    red[tid] = sum;
    __syncthreads();
    for (int off = 128; off > 0; off >>= 1) {
        if (tid < off) red[tid] += red[tid + off];
        __syncthreads();
    }
    const float inv = 1.f / red[0];
    if (tid < 240) {
        e.x *= inv; e.y *= inv; e.z *= inv; e.w *= inv;
        *(float4*)(p + tid * 4) = e;
    }
}

// ctx[zb][n,c] = 0.25 * sum_h sum_k P[zb,h][c,k] * V[zb,h][n,k]
__global__ __launch_bounds__(256) void k_pv(const float* __restrict__ V,
                                            const float* __restrict__ S,
                                            float* __restrict__ ctx)
{
    __shared__ float As[BK][BM + 4], Bs[BK][BN + 4];
    const int z = blockIdx.z;  // local b
    const int m0 = blockIdx.y * BM, n0 = blockIdx.x * BN;
    float acc[4][4] = {};
    for (int h = 0; h < 4; ++h) {
        const float* A = V + (size_t)(z * 4 + h) * 196 * 960;
        const float* B = S + (size_t)(z * 4 + h) * 960 * 960;
        gemm_tile(A, 960, 196, B, 960, 960, 960, m0, n0, acc, As, Bs);
    }
    store_tile(ctx + (size_t)z * 196 * 960, 960, 196, 960, m0, n0, acc, 0.25f);
}

// O_i[b][n,c'] = sum_c ctx[b][n, coff+c] * Wo_i[c',c]
__global__ __launch_bounds__(256) void k_o(const float* __restrict__ ctx,
                                           const float* __restrict__ Wo,
                                           float* __restrict__ outp,
                                           int b0, int Ci, int coff)
{
    __shared__ float As[BK][BM + 4], Bs[BK][BN + 4];
    const int z = blockIdx.z, b = b0 + z;
    const int m0 = blockIdx.y * BM, n0 = blockIdx.x * BN;
    const float* A = ctx + (size_t)z * 196 * 960 + coff;
    float acc[4][4] = {};
    gemm_tile(A, 960, 196, Wo, Ci, Ci, Ci, m0, n0, acc, As, Bs);
    store_tile(outp + (size_t)b * 196 * Ci, Ci, 196, Ci, m0, n0, acc, 1.f);
}

// ---------------------------------------------------------------------------
extern "C" void kernel_launch(void* const* d_in, const int* in_sizes, int n_in,
                              void* d_out, int out_size, void* d_ws, size_t ws_size,
                              hipStream_t stream)
{
    const float* e1   = (const float*)d_in[0];
    const float* e2   = (const float*)d_in[1];
    const float* e3   = (const float*)d_in[2];
    const float* e4   = (const float*)d_in[3];
    const float* eall = (const float*)d_in[4];
    const float* Wq1  = (const float*)d_in[5];
    const float* Wq2  = (const float*)d_in[6];
    const float* Wq3  = (const float*)d_in[7];
    const float* Wq4  = (const float*)d_in[8];
    const float* Wk   = (const float*)d_in[9];
    const float* Wv   = (const float*)d_in[10];
    const float* Wo1  = (const float*)d_in[11];
    const float* Wo2  = (const float*)d_in[12];
    const float* Wo3  = (const float*)d_in[13];
    const float* Wo4  = (const float*)d_in[14];
    float* out = (float*)d_out;

    const size_t perB_Kt  = (size_t)4 * 960 * 196;  // floats (also V, Qt)
    const size_t perB_S   = (size_t)4 * 960 * 960;
    const size_t perB_ctx = (size_t)196 * 960;
    const size_t perB_st  = 32;
    const size_t perB_bytes = (perB_Kt * 3 + perB_S + perB_ctx + perB_st) * 4;

    int Bc = (int)(ws_size / perB_bytes);
    if (Bc > 32) Bc = 32;
    if (Bc < 1)  Bc = 1;   // hope ws >= ~25MB

    float* Kt  = (float*)d_ws;
    float* V   = Kt  + perB_Kt * Bc;
    float* Qt  = V   + perB_Kt * Bc;
    float* S   = Qt  + perB_Kt * Bc;
    float* ctx = S   + perB_S * Bc;
    float* st  = ctx + perB_ctx * Bc;

    const dim3 blk(256);
    for (int b0 = 0; b0 < 32; b0 += Bc) {
        const int bc = (32 - b0 < Bc) ? (32 - b0) : Bc;
        hipMemsetAsync(st, 0, (size_t)bc * perB_st * 4, stream);
        k_kt<<<dim3(4, 15, bc * 4), blk, 0, stream>>>(eall, Wk, Kt, b0);
        k_v <<<dim3(15, 4, bc * 4), blk, 0, stream>>>(eall, Wv, V, b0);
        k_q <<<dim3(4, 15, bc * 4), blk, 0, stream>>>(e1, e2, e3, e4,
                                                      Wq1, Wq2, Wq3, Wq4, Qt, b0);
        k_s <<<dim3(15, 15, bc * 4), blk, 0, stream>>>(Qt, Kt, S, st);
        k_sm<<<dim3(bc * 4 * 960), blk, 0, stream>>>(S, st);
        k_pv<<<dim3(15, 4, bc), blk, 0, stream>>>(V, S, ctx);
        k_o <<<dim3(1, 4, bc), blk, 0, stream>>>(ctx, Wo1, out + 0,                     b0, 64,  0);
        k_o <<<dim3(2, 4, bc), blk, 0, stream>>>(ctx, Wo2, out + (size_t)32*196*64,     b0, 128, 64);
        k_o <<<dim3(4, 4, bc), blk, 0, stream>>>(ctx, Wo3, out + (size_t)32*196*192,    b0, 256, 192);
        k_o <<<dim3(8, 4, bc), blk, 0, stream>>>(ctx, Wo4, out + (size_t)32*196*448,    b0, 512, 448);
    }
}

// Round 2
// 880.812 us; speedup vs baseline: 5.5670x; 5.5670x over previous
//
#include <hip/hip_runtime.h>
#include <math.h>

typedef __attribute__((ext_vector_type(8))) short bf16x8;   // 8 bf16 in 4 VGPRs
typedef __attribute__((ext_vector_type(4))) float f32x4;
typedef unsigned short u16;

__device__ __forceinline__ u16 f2bf(float f) {
  unsigned u = __float_as_uint(f);
  return (u16)((u + 0x7FFFu + ((u >> 16) & 1u)) >> 16);   // RNE
}
__device__ __forceinline__ float bf2f(u16 h) {
  return __uint_as_float(((unsigned)h) << 16);
}

__device__ __forceinline__ void gload16(const u16* g, void* lds) {
  __builtin_amdgcn_global_load_lds(
      (const __attribute__((address_space(1))) unsigned int*)g,
      (__attribute__((address_space(3))) unsigned int*)lds, 16, 0, 0);
}

// ---------------------------------------------------------------------------
// MFMA core: 128x128 tile, BK=32, 256 threads (4 waves, each a 64x64 quadrant
// of 4x4 16x16 fragments). A,B pre-offset to (m0,0)/(n0,0); row strides lda/ldb
// (elements); K multiple of 32; all addresses must be in-bounds (padded bufs).
// LDS: As/Bs 128x32 bf16 row-major (linear, matches global_load_lds lane order).
// ---------------------------------------------------------------------------
__device__ __forceinline__ void mfma_core(
    const u16* __restrict__ A, int lda,
    const u16* __restrict__ B, int ldb,
    int K, f32x4 (&acc)[4][4], u16* As, u16* Bs)
{
  const int tid = threadIdx.x;
  const int l = tid & 63, w = tid >> 6;
  const int srow = w * 16 + (l >> 2);     // staging row (+64 for 2nd issue)
  const int kel  = (l & 3) * 8;           // staging k-element
  char* AsB = (char*)As + w * 1024;
  char* BsB = (char*)Bs + w * 1024;
  const u16* Ap  = A + (size_t)srow * lda + kel;
  const u16* Ap2 = A + (size_t)(srow + 64) * lda + kel;
  const u16* Bp  = B + (size_t)srow * ldb + kel;
  const u16* Bp2 = B + (size_t)(srow + 64) * ldb + kel;
  const int wm = w >> 1, wn = w & 1;
  const int aoff = (wm * 64 + (l & 15)) * 32 + (l >> 4) * 8;
  const int boff = (wn * 64 + (l & 15)) * 32 + (l >> 4) * 8;
  for (int kb = 0; kb < K; kb += 32) {
    __syncthreads();
    gload16(Ap + kb,  AsB);
    gload16(Ap2 + kb, AsB + 4096);
    gload16(Bp + kb,  BsB);
    gload16(Bp2 + kb, BsB + 4096);
    __syncthreads();
    bf16x8 av[4], bv[4];
#pragma unroll
    for (int i = 0; i < 4; ++i) {
      av[i] = *(const bf16x8*)(As + aoff + i * 16 * 32);
      bv[i] = *(const bf16x8*)(Bs + boff + i * 16 * 32);
    }
#pragma unroll
    for (int i = 0; i < 4; ++i)
#pragma unroll
      for (int j = 0; j < 4; ++j)
        acc[i][j] = __builtin_amdgcn_mfma_f32_16x16x32_bf16(av[i], bv[j], acc[i][j], 0, 0, 0);
  }
}

// ---------------------------------------------------------------------------
// f32 -> bf16 pad-copy: dst[g][rr][c] = rr<srcR ? src[g][rr][c] : 0
// ---------------------------------------------------------------------------
__global__ __launch_bounds__(256) void k_padcvt(
    const float* __restrict__ src, u16* __restrict__ dst,
    int srcR, int dstR, int C, long long dstStride, long long dstOff, long long total)
{
  long long idx = (long long)blockIdx.x * 256 + threadIdx.x;
  if (idx >= total) return;
  long long per = (long long)dstR * C;
  int g  = (int)(idx / per);
  int r2 = (int)(idx % per);
  int rr = r2 / C, c = r2 - rr * C;
  float v = (rr < srcR) ? src[((long long)g * srcR + rr) * C + c] : 0.f;
  dst[g * dstStride + dstOff + (long long)rr * C + c] = f2bf(v);
}

// Kt[h][o(1024)][NB] = Wk[h] x embA^T
__global__ __launch_bounds__(256) void k_kt(const u16* __restrict__ embA,
    const u16* __restrict__ WkB, u16* __restrict__ Kt, int b0, int NB)
{
  __shared__ u16 As[128 * 32], Bs[128 * 32];
  const int h = blockIdx.z;
  const int m0 = blockIdx.y * 128, n0 = blockIdx.x * 128;
  const u16* A = WkB + (size_t)h * 1024 * 960 + (size_t)m0 * 960;
  const u16* B = embA + (size_t)(b0 * 224 + n0) * 960;
  f32x4 acc[4][4] = {};
  mfma_core(A, 960, B, 960, 960, acc, As, Bs);
  const int tid = threadIdx.x, l = tid & 63, w = tid >> 6, wm = w >> 1, wn = w & 1;
  u16* C = Kt + (size_t)h * 1024 * NB;
#pragma unroll
  for (int i = 0; i < 4; ++i) {
    const int gm0 = m0 + wm * 64 + i * 16 + (l >> 4) * 4;
#pragma unroll
    for (int j = 0; j < 4; ++j) {
      const int n = n0 + wn * 64 + j * 16 + (l & 15);
#pragma unroll
      for (int r = 0; r < 4; ++r)
        C[(size_t)(gm0 + r) * NB + n] = f2bf(acc[i][j][r]);
    }
  }
}

// V[lb][h][n(256 pad)][o(1024)] = embA x Wv[h]^T
__global__ __launch_bounds__(256) void k_v(const u16* __restrict__ embA,
    const u16* __restrict__ WvB, u16* __restrict__ V, int b0, int NB)
{
  __shared__ u16 As[128 * 32], Bs[128 * 32];
  const int h = blockIdx.z;
  const int m0 = blockIdx.y * 128, n0 = blockIdx.x * 128;
  const u16* A = embA + (size_t)(b0 * 224 + m0) * 960;
  const u16* B = WvB + (size_t)h * 1024 * 960 + (size_t)n0 * 960;
  f32x4 acc[4][4] = {};
  mfma_core(A, 960, B, 960, 960, acc, As, Bs);
  const int tid = threadIdx.x, l = tid & 63, w = tid >> 6, wm = w >> 1, wn = w & 1;
#pragma unroll
  for (int i = 0; i < 4; ++i) {
    const int t0 = m0 + wm * 64 + i * 16 + (l >> 4) * 4;
#pragma unroll
    for (int r = 0; r < 4; ++r) {
      const int t = t0 + r;
      const int lb = t / 224, n = t - lb * 224;
      u16* C = V + ((size_t)(lb * 4 + h) * 256 + n) * 1024;
#pragma unroll
      for (int j = 0; j < 4; ++j) {
        const int col = n0 + wn * 64 + j * 16 + (l & 15);
        C[col] = f2bf(acc[i][j][r]);
      }
    }
  }
}

// Qt[h][ccat(1024)][NB] = Wq_br[h] x emb_br^T  (store-guarded per branch rows)
__global__ __launch_bounds__(256) void k_q(
    const u16* __restrict__ e1b, const u16* __restrict__ e2b,
    const u16* __restrict__ e3b, const u16* __restrict__ e4b,
    const u16* __restrict__ WqB, u16* __restrict__ Qt, int b0, int NB)
{
  __shared__ u16 As[128 * 32], Bs[128 * 32];
  const int h = blockIdx.z;
  const int y = blockIdx.y;
  const int br = (y == 0) ? 0 : (y == 1) ? 1 : (y < 4) ? 2 : 3;
  const int mt = (y <= 1) ? 0 : (y < 4) ? (y - 2) : (y - 4);
  const int Ci = 64 << br;
  const int coff = (br == 0) ? 0 : (br == 1) ? 64 : (br == 2) ? 192 : 448;
  const int wqo = (br == 0) ? 0 : (br == 1) ? 8192 : (br == 2) ? 24576 : 90112;
  const u16* eb = (br == 0) ? e1b : (br == 1) ? e2b : (br == 2) ? e3b : e4b;
  const int n0 = blockIdx.x * 128;
  const u16* A = WqB + (size_t)h * 352256 + wqo + (size_t)mt * 128 * Ci;
  const u16* B = eb + (size_t)(b0 * 224 + n0) * Ci;
  f32x4 acc[4][4] = {};
  mfma_core(A, Ci, B, Ci, Ci, acc, As, Bs);
  const int tid = threadIdx.x, l = tid & 63, w = tid >> 6, wm = w >> 1, wn = w & 1;
  u16* C = Qt + (size_t)h * 1024 * NB;
#pragma unroll
  for (int i = 0; i < 4; ++i) {
    const int lr0 = mt * 128 + wm * 64 + i * 16 + (l >> 4) * 4;
#pragma unroll
    for (int j = 0; j < 4; ++j) {
      const int n = n0 + wn * 64 + j * 16 + (l & 15);
#pragma unroll
      for (int r = 0; r < 4; ++r)
        if (lr0 + r < Ci)
          C[(size_t)(coff + lr0 + r) * NB + n] = f2bf(acc[i][j][r]);
    }
  }
}

// S[z][c(1024)][o(1024)] = (Qt . Kt^T)/sqrt(960), + per-(z,branch) sum/sumsq
__global__ __launch_bounds__(256) void k_s(const u16* __restrict__ Qt,
    const u16* __restrict__ Kt, u16* __restrict__ S, float* __restrict__ stats,
    int NB)
{
  __shared__ u16 As[128 * 32], Bs[128 * 32];
  __shared__ float sb[8];
  const int tid = threadIdx.x;
  if (tid < 8) sb[tid] = 0.f;
  const int z = blockIdx.z;           // lb*4 + h
  const int lb = z >> 2, h = z & 3;
  const int m0 = blockIdx.y * 128, n0 = blockIdx.x * 128;
  const u16* A = Qt + (size_t)h * 1024 * NB + (size_t)m0 * NB + lb * 224;
  const u16* B = Kt + (size_t)h * 1024 * NB + (size_t)n0 * NB + lb * 224;
  f32x4 acc[4][4] = {};
  mfma_core(A, NB, B, NB, 224, acc, As, Bs);
  const int l = tid & 63, w = tid >> 6, wm = w >> 1, wn = w & 1;
  u16* C = S + (size_t)z * 1024 * 1024;
  const float scale = 0.03227486121839514f;   // 1/sqrt(960)
#pragma unroll
  for (int i = 0; i < 4; ++i) {
    const int gm0 = m0 + wm * 64 + i * 16 + (l >> 4) * 4;
    const int br = (gm0 < 64) ? 0 : (gm0 < 192) ? 1 : (gm0 < 448) ? 2 : 3;
    float sv = 0.f, qv = 0.f;
#pragma unroll
    for (int j = 0; j < 4; ++j) {
      const int n = n0 + wn * 64 + j * 16 + (l & 15);
#pragma unroll
      for (int r = 0; r < 4; ++r) {
        const float v = acc[i][j][r] * scale;
        C[(size_t)(gm0 + r) * 1024 + n] = f2bf(v);
        sv += v; qv += v * v;
      }
    }
    if (gm0 < 960) {                 // exclude never-written Qt pad rows
      atomicAdd(&sb[br * 2], sv);
      atomicAdd(&sb[br * 2 + 1], qv);
    }
  }
  __syncthreads();
  if (tid < 8) atomicAdd(stats + (size_t)z * 8 + tid, sb[tid]);
}

// Row softmax with InstanceNorm temperature (mean cancels; rs = rsqrt(var+eps)).
// One wave per row of 960 real cols (cols 960..1023 are exact zeros, masked).
__global__ __launch_bounds__(256) void k_sm(u16* __restrict__ S,
                                            const float* __restrict__ stats)
{
  const int tid = threadIdx.x, l = tid & 63;
  const int ri = blockIdx.x * 4 + (tid >> 6);
  const int z = ri / 960, c = ri - (ri / 960) * 960;
  const int br = (c < 64) ? 0 : (c < 192) ? 1 : (c < 448) ? 2 : 3;
  const float cnt = (float)(64 << br) * 960.f;
  const float s0 = stats[z * 8 + br * 2], s1 = stats[z * 8 + br * 2 + 1];
  const float mean = s0 / cnt;
  const float var = s1 / cnt - mean * mean;
  const float rs = rsqrtf(var + 1e-5f);
  u16* row = S + (size_t)(z * 1024 + c) * 1024;
  const bool ok1 = (l < 56);          // lanes 56..63 second-chunk cols >= 960
  bf16x8 v0 = *(const bf16x8*)(row + l * 8);
  bf16x8 v1 = *(const bf16x8*)(row + 512 + l * 8);
  float x0[8], x1[8];
#pragma unroll
  for (int i = 0; i < 8; ++i) x0[i] = bf2f((u16)v0[i]) * rs;
#pragma unroll
  for (int i = 0; i < 8; ++i) x1[i] = bf2f((u16)v1[i]) * rs;
  float m = -1e30f;
#pragma unroll
  for (int i = 0; i < 8; ++i) m = fmaxf(m, x0[i]);
  if (ok1) {
#pragma unroll
    for (int i = 0; i < 8; ++i) m = fmaxf(m, x1[i]);
  }
#pragma unroll
  for (int off = 32; off > 0; off >>= 1) m = fmaxf(m, __shfl_xor(m, off, 64));
  float e0[8], e1[8], s = 0.f;
#pragma unroll
  for (int i = 0; i < 8; ++i) { e0[i] = __expf(x0[i] - m); s += e0[i]; }
#pragma unroll
  for (int i = 0; i < 8; ++i) { e1[i] = ok1 ? __expf(x1[i] - m) : 0.f; s += e1[i]; }
#pragma unroll
  for (int off = 32; off > 0; off >>= 1) s += __shfl_xor(s, off, 64);
  const float inv = 1.f / s;
  bf16x8 o0, o1;
#pragma unroll
  for (int i = 0; i < 8; ++i) o0[i] = (short)f2bf(e0[i] * inv);
#pragma unroll
  for (int i = 0; i < 8; ++i) o1[i] = (short)f2bf(e1[i] * inv);
  *(bf16x8*)(row + l * 8) = o0;
  if (ok1) *(bf16x8*)(row + 512 + l * 8) = o1;
}

// ctxh[z][n(224)][c(1024)] = V[z] . P[z]^T   (f32 partial per head)
__global__ __launch_bounds__(256) void k_pv(const u16* __restrict__ V,
    const u16* __restrict__ S, float* __restrict__ ctxh)
{
  __shared__ u16 As[128 * 32], Bs[128 * 32];
  const int z = blockIdx.z;
  const int m0 = blockIdx.y * 128, n0 = blockIdx.x * 128;
  const u16* A = V + (size_t)z * 256 * 1024 + (size_t)m0 * 1024;
  const u16* B = S + (size_t)z * 1024 * 1024 + (size_t)n0 * 1024;
  f32x4 acc[4][4] = {};
  mfma_core(A, 1024, B, 1024, 960, acc, As, Bs);
  const int tid = threadIdx.x, l = tid & 63, w = tid >> 6, wm = w >> 1, wn = w & 1;
  float* C = ctxh + (size_t)z * 224 * 1024;
#pragma unroll
  for (int i = 0; i < 4; ++i) {
    const int gm0 = m0 + wm * 64 + i * 16 + (l >> 4) * 4;
#pragma unroll
    for (int j = 0; j < 4; ++j) {
      const int n = n0 + wn * 64 + j * 16 + (l & 15);
#pragma unroll
      for (int r = 0; r < 4; ++r)
        if (gm0 + r < 224)
          C[(size_t)(gm0 + r) * 1024 + n] = acc[i][j][r];
    }
  }
}

// ctx[lb][n][c] = bf16( 0.25 * sum_h ctxh[lb][h][n][c] )
__global__ __launch_bounds__(256) void k_ctxred(const float* __restrict__ ctxh,
    u16* __restrict__ ctx, int Bc)
{
  const long long t4 = ((long long)blockIdx.x * 256 + threadIdx.x) * 4;
  if (t4 >= (long long)Bc * 229376) return;
  const int lb = (int)(t4 / 229376);
  const int r = (int)(t4 - (long long)lb * 229376);
  const float* p = ctxh + (size_t)lb * 4 * 229376 + r;
  f32x4 a = *(const f32x4*)p;
  a += *(const f32x4*)(p + 229376);
  a += *(const f32x4*)(p + 2 * 229376);
  a += *(const f32x4*)(p + 3 * 229376);
  u16* d = ctx + (size_t)lb * 262144 + r;
  d[0] = f2bf(a[0] * 0.25f);
  d[1] = f2bf(a[1] * 0.25f);
  d[2] = f2bf(a[2] * 0.25f);
  d[3] = f2bf(a[3] * 0.25f);
}

// O_br[b][n][c'] = ctx[b][n, coff:coff+Ci] . Wo_br^T   (f32 to d_out)
__global__ __launch_bounds__(256) void k_o(const u16* __restrict__ ctx,
    const u16* __restrict__ WoB, float* __restrict__ out, int b0)
{
  __shared__ u16 As[128 * 32], Bs[128 * 32];
  const int lb = blockIdx.z;
  const int x = blockIdx.x;
  const int br = (x == 0) ? 0 : (x == 1) ? 1 : (x < 4) ? 2 : 3;
  const int nt = (x <= 1) ? 0 : (x < 4) ? (x - 2) : (x - 4);
  const int Ci = 64 << br;
  const int coff = (br == 0) ? 0 : (br == 1) ? 64 : (br == 2) ? 192 : 448;
  const int woo = (br == 0) ? 0 : (br == 1) ? 8192 : (br == 2) ? 24576 : 90112;
  const long long ob = (br == 0) ? 0LL : (br == 1) ? 401408LL : (br == 2) ? 1204224LL : 2809856LL;
  const int m0 = blockIdx.y * 128;
  const u16* A = ctx + (size_t)lb * 262144 + (size_t)m0 * 1024 + coff;
  const u16* B = WoB + woo + (size_t)nt * 128 * Ci;
  f32x4 acc[4][4] = {};
  mfma_core(A, 1024, B, Ci, Ci, acc, As, Bs);
  const int tid = threadIdx.x, l = tid & 63, w = tid >> 6, wm = w >> 1, wn = w & 1;
  float* O = out + ob;
  const int gb = b0 + lb;
#pragma unroll
  for (int i = 0; i < 4; ++i) {
    const int row0 = m0 + wm * 64 + i * 16 + (l >> 4) * 4;
#pragma unroll
    for (int j = 0; j < 4; ++j) {
      const int cg = nt * 128 + wn * 64 + j * 16 + (l & 15);
#pragma unroll
      for (int r = 0; r < 4; ++r) {
        const int row = row0 + r;
        if (row < 196 && cg < Ci)
          O[((size_t)gb * 196 + row) * Ci + cg] = acc[i][j][r];
      }
    }
  }
}

// ---------------------------------------------------------------------------
extern "C" void kernel_launch(void* const* d_in, const int* in_sizes, int n_in,
                              void* d_out, int out_size, void* d_ws, size_t ws_size,
                              hipStream_t stream)
{
  const float* e1  = (const float*)d_in[0];
  const float* e2  = (const float*)d_in[1];
  const float* e3  = (const float*)d_in[2];
  const float* e4  = (const float*)d_in[3];
  const float* eall = (const float*)d_in[4];
  const float* Wq1 = (const float*)d_in[5];
  const float* Wq2 = (const float*)d_in[6];
  const float* Wq3 = (const float*)d_in[7];
  const float* Wq4 = (const float*)d_in[8];
  const float* Wk  = (const float*)d_in[9];
  const float* Wv  = (const float*)d_in[10];
  const float* Wo1 = (const float*)d_in[11];
  const float* Wo2 = (const float*)d_in[12];
  const float* Wo3 = (const float*)d_in[13];
  const float* Wo4 = (const float*)d_in[14];
  float* out = (float*)d_out;

  char* p = (char*)d_ws;
  auto alloc = [&](size_t bytes) -> void* {
    void* r = p; p += (bytes + 255) & ~(size_t)255; return r;
  };
  u16* embA = (u16*)alloc((size_t)7168 * 960 * 2);
  u16* e1b  = (u16*)alloc((size_t)7168 * 64 * 2);
  u16* e2b  = (u16*)alloc((size_t)7168 * 128 * 2);
  u16* e3b  = (u16*)alloc((size_t)7168 * 256 * 2);
  u16* e4b  = (u16*)alloc((size_t)7168 * 512 * 2);
  u16* WkB  = (u16*)alloc((size_t)4 * 1024 * 960 * 2);
  u16* WvB  = (u16*)alloc((size_t)4 * 1024 * 960 * 2);
  u16* WqB  = (u16*)alloc((size_t)4 * 352256 * 2);
  u16* WoB  = (u16*)alloc((size_t)352256 * 2);
  const size_t persist = (size_t)(p - (char*)d_ws);
  // per-batch chunk bytes: Kt+Qt + V + S + ctx (bf16) + ctxh (f32) + stats
  const size_t perBatch = (size_t)(1835008 + 1048576 + 4194304 + 262144) * 2
                        + (size_t)917504 * 4 + 128 + 4096;
  int Bc = 4;
  if      (persist + 32 * perBatch <= ws_size) Bc = 32;
  else if (persist + 16 * perBatch <= ws_size) Bc = 16;
  else if (persist +  8 * perBatch <= ws_size) Bc = 8;
  const int NB = Bc * 224;

  u16* Kt  = (u16*)alloc((size_t)4 * 1024 * NB * 2);
  u16* Qt  = (u16*)alloc((size_t)4 * 1024 * NB * 2);
  u16* V   = (u16*)alloc((size_t)Bc * 4 * 256 * 1024 * 2);
  u16* S   = (u16*)alloc((size_t)Bc * 4 * 1024 * 1024 * 2);
  float* ctxh = (float*)alloc((size_t)Bc * 4 * 224 * 1024 * 4);
  u16* ctx = (u16*)alloc((size_t)Bc * 256 * 1024 * 2);
  float* stats = (float*)alloc((size_t)Bc * 32 * 4);

  const dim3 blk(256);
  auto cvt = [&](const float* src, u16* dst, int srcR, int dstR, int C,
                 long long stride, long long off, int g) {
    long long total = (long long)g * dstR * C;
    int gridc = (int)((total + 255) / 256);
    k_padcvt<<<dim3(gridc), blk, 0, stream>>>(src, dst, srcR, dstR, C, stride, off, total);
  };
  cvt(eall, embA, 196, 224, 960, (long long)224 * 960, 0, 32);
  cvt(e1, e1b, 196, 224, 64,  (long long)224 * 64,  0, 32);
  cvt(e2, e2b, 196, 224, 128, (long long)224 * 128, 0, 32);
  cvt(e3, e3b, 196, 224, 256, (long long)224 * 256, 0, 32);
  cvt(e4, e4b, 196, 224, 512, (long long)224 * 512, 0, 32);
  cvt(Wk, WkB, 960, 1024, 960, (long long)1024 * 960, 0, 4);
  cvt(Wv, WvB, 960, 1024, 960, (long long)1024 * 960, 0, 4);
  cvt(Wq1, WqB, 64, 128, 64,   352256, 0,     4);
  cvt(Wq2, WqB, 128, 128, 128, 352256, 8192,  4);
  cvt(Wq3, WqB, 256, 256, 256, 352256, 24576, 4);
  cvt(Wq4, WqB, 512, 512, 512, 352256, 90112, 4);
  cvt(Wo1, WoB, 64, 128, 64,   0, 0,     1);
  cvt(Wo2, WoB, 128, 128, 128, 0, 8192,  1);
  cvt(Wo3, WoB, 256, 256, 256, 0, 24576, 1);
  cvt(Wo4, WoB, 512, 512, 512, 0, 90112, 1);

  const int NT = NB / 128;   // NB = Bc*224, Bc in {4,8,16,32} -> divisible by 128
  for (int b0 = 0; b0 < 32; b0 += Bc) {
    hipMemsetAsync(stats, 0, (size_t)Bc * 32 * 4, stream);
    k_kt<<<dim3(NT, 8, 4), blk, 0, stream>>>(embA, WkB, Kt, b0, NB);
    k_v <<<dim3(8, NT, 4), blk, 0, stream>>>(embA, WvB, V, b0, NB);
    k_q <<<dim3(NT, 8, 4), blk, 0, stream>>>(e1b, e2b, e3b, e4b, WqB, Qt, b0, NB);
    k_s <<<dim3(8, 8, Bc * 4), blk, 0, stream>>>(Qt, Kt, S, stats, NB);
    k_sm<<<dim3(Bc * 960), blk, 0, stream>>>(S, stats);
    k_pv<<<dim3(8, 2, Bc * 4), blk, 0, stream>>>(V, S, ctxh);
    k_ctxred<<<dim3((Bc * 229376 / 4 + 255) / 256), blk, 0, stream>>>(ctxh, ctx, Bc);
    k_o <<<dim3(8, 2, Bc), blk, 0, stream>>>(ctx, WoB, out, b0);
  }
}